// Round 1
// baseline (308.863 us; speedup 1.0000x reference)
//
#include <hip/hip_runtime.h>

// Shapes (fixed by the problem)
#define LQ 64
#define LK 128
#define LL 192
#define DD 128
#define FF 2048

typedef __attribute__((__ext_vector_type__(8))) __bf16 bf16x8;
typedef __attribute__((__ext_vector_type__(4))) __bf16 bf16x4;
typedef __attribute__((__ext_vector_type__(4))) float  f32x4;

#define MFMA(a, b, c) __builtin_amdgcn_mfma_f32_16x16x32_bf16((a), (b), (c), 0, 0, 0)

// ---------------------------------------------------------------------------
// A0: prep — sigmoid(score_embed) as bf16, bf16 copies of fc0_w / fc2_w,
//     combined per-ff constants for the fused fc2/bn2/relu/fc3 epilogue.
// ---------------------------------------------------------------------------
__global__ void prep_kernel(const float* __restrict__ se,
                            const float* __restrict__ fc0w,
                            const float* __restrict__ fc2w,
                            const float* __restrict__ fc2b,
                            const float* __restrict__ bn2g,
                            const float* __restrict__ bn2b,
                            const float* __restrict__ fc3w,
                            __bf16* __restrict__ sig_bf,
                            __bf16* __restrict__ fc0w_bf,
                            __bf16* __restrict__ fc2w_bf,
                            float* __restrict__ h2,
                            float* __restrict__ bb2,
                            float* __restrict__ f3)
{
    int i0 = blockIdx.x * blockDim.x + threadIdx.x;
    int stride = gridDim.x * blockDim.x;
    const float c1 = rsqrtf(1.f + 1e-5f);
    for (int i = i0; i < LL * LL; i += stride)
        sig_bf[i] = (__bf16)(1.f / (1.f + __expf(-se[i])));
    for (int i = i0; i < DD * DD; i += stride)
        fc0w_bf[i] = (__bf16)fc0w[i];
    for (int i = i0; i < FF * LL; i += stride)
        fc2w_bf[i] = (__bf16)fc2w[i];
    for (int i = i0; i < FF; i += stride) {
        float h = bn2g[i] * c1;           // bn2 scale (beta2 added below)
        h2[i]  = h;
        bb2[i] = fc2b[i] * h + bn2b[i];   // (dot + fc2b)*h + beta2 = dot*h + bb2
        f3[i]  = fc3w[i];
    }
}

// ---------------------------------------------------------------------------
// A1: query/key projection  y = X @ fc0_w^T + fc0_b, output bf16 [36864][128]
//     rows 0..12287 = query (from q_feat), 12288..36863 = key (from g_feat)
// ---------------------------------------------------------------------------
__launch_bounds__(256, 2)
__global__ void qkproj_kernel(const float* __restrict__ qf,
                              const float* __restrict__ gf,
                              const __bf16* __restrict__ w_bf,
                              const float* __restrict__ bias,
                              __bf16* __restrict__ qk_bf)
{
    __shared__ __bf16 Xs[32][136];    // 32 rows x 128 (+8 pad)
    __shared__ __bf16 Ws[128][136];   // fc0_w row-major [out_c][k]
    int bx = blockIdx.x, tid = threadIdx.x;
    const float* src = (bx < 384) ? (qf + (size_t)bx * (32 * 128))
                                  : (gf + (size_t)(bx - 384) * (32 * 128));
#pragma unroll
    for (int it = 0; it < 4; ++it) {             // 4096 floats
        int e = (it * 256 + tid) * 4;
        int r = e >> 7, c = e & 127;
        float4 v = *reinterpret_cast<const float4*>(src + e);
        bf16x4 xv;
        xv[0] = (__bf16)v.x; xv[1] = (__bf16)v.y;
        xv[2] = (__bf16)v.z; xv[3] = (__bf16)v.w;
        *reinterpret_cast<bf16x4*>(&Xs[r][c]) = xv;
    }
#pragma unroll
    for (int it = 0; it < 8; ++it) {             // 16384 bf16
        int e = (it * 256 + tid) * 8;
        int r = e >> 7, c = e & 127;
        *reinterpret_cast<bf16x8*>(&Ws[r][c]) =
            *reinterpret_cast<const bf16x8*>(w_bf + e);
    }
    __syncthreads();

    int wv = tid >> 6, lane = tid & 63, quad = lane >> 4, l16 = lane & 15;
    int n0 = wv * 32;                            // wave's 32 output cols
    f32x4 acc[2][2];
#pragma unroll
    for (int m = 0; m < 2; ++m)
#pragma unroll
        for (int n = 0; n < 2; ++n) acc[m][n] = (f32x4){0.f, 0.f, 0.f, 0.f};
#pragma unroll
    for (int ks = 0; ks < 4; ++ks) {
        bf16x8 a0 = *reinterpret_cast<const bf16x8*>(&Xs[l16][ks * 32 + quad * 8]);
        bf16x8 a1 = *reinterpret_cast<const bf16x8*>(&Xs[16 + l16][ks * 32 + quad * 8]);
        bf16x8 b0 = *reinterpret_cast<const bf16x8*>(&Ws[n0 + l16][ks * 32 + quad * 8]);
        bf16x8 b1 = *reinterpret_cast<const bf16x8*>(&Ws[n0 + 16 + l16][ks * 32 + quad * 8]);
        acc[0][0] = MFMA(a0, b0, acc[0][0]);
        acc[0][1] = MFMA(a0, b1, acc[0][1]);
        acc[1][0] = MFMA(a1, b0, acc[1][0]);
        acc[1][1] = MFMA(a1, b1, acc[1][1]);
    }
#pragma unroll
    for (int mt = 0; mt < 2; ++mt)
#pragma unroll
        for (int nt = 0; nt < 2; ++nt) {
            int colg = n0 + nt * 16 + l16;
            float bv = bias[colg];
#pragma unroll
            for (int r = 0; r < 4; ++r) {
                int rowg = bx * 32 + mt * 16 + quad * 4 + r;
                qk_bf[(size_t)rowg * 128 + colg] = (__bf16)(acc[mt][nt][r] + bv);
            }
        }
}

// ---------------------------------------------------------------------------
// B: per-pair score GEMM + sigmoid-modulation + dual max-reduce (dominant).
//    One block per (q, 8 keys). 4 waves: 2x2 grid of 96x96 quadrants.
//    S[s][t] = sum_d key[s][d]*query[t][d] * sig[s][t]
//    Sred row 2p   = max over s (indexed by t)
//    Sred row 2p+1 = max over t (indexed by s),  both * bn1 scale + bn1 bias
// ---------------------------------------------------------------------------
__launch_bounds__(256, 1)
__global__ void score_kernel(const __bf16* __restrict__ qk_bf,
                             const __bf16* __restrict__ sig_bf,
                             const float* __restrict__ bn1g,
                             const float* __restrict__ bn1b,
                             __bf16* __restrict__ Sred)
{
    __shared__ __bf16 Qs[192][136];   // query rows [t][d], +8 pad
    __shared__ __bf16 Ks[192][136];   // key rows   [s][d], +8 pad
    __shared__ float  red2[192][36];  // per-s partial maxes, 32 cols (+4 pad)
    __shared__ float  redT[192][2];   // per-t partial maxes from the 2 s-halves

    int tid = threadIdx.x;
    int q = blockIdx.x >> 4;
    int kbase = (blockIdx.x & 15) << 3;

    const __bf16* qsrc = qk_bf + (size_t)q * (192 * 128);
#pragma unroll
    for (int it = 0; it < 12; ++it) {            // 24576 bf16
        int e = (it * 256 + tid) * 8;
        int r = e >> 7, c = e & 127;
        *reinterpret_cast<bf16x8*>(&Qs[r][c]) =
            *reinterpret_cast<const bf16x8*>(qsrc + e);
    }
    const float g1c = bn1g[0] * rsqrtf(1.f + 1e-5f);
    const float b1v = bn1b[0];

    int wv = tid >> 6, lane = tid & 63, quad = lane >> 4, l16 = lane & 15;
    int ws = wv >> 1, wt = wv & 1;
    int sbase = ws * 96, tbase = wt * 96;

    for (int kk = 0; kk < 8; ++kk) {
        int kidx = kbase + kk;
        const __bf16* ksrc = qk_bf + (size_t)(12288 + kidx * 192) * 128;
#pragma unroll
        for (int it = 0; it < 12; ++it) {
            int e = (it * 256 + tid) * 8;
            int r = e >> 7, c = e & 127;
            *reinterpret_cast<bf16x8*>(&Ks[r][c]) =
                *reinterpret_cast<const bf16x8*>(ksrc + e);
        }
        __syncthreads();   // Ks ready (also first-iter Qs)

        f32x4 acc[6][6];
#pragma unroll
        for (int i = 0; i < 6; ++i)
#pragma unroll
            for (int j = 0; j < 6; ++j) acc[i][j] = (f32x4){0.f, 0.f, 0.f, 0.f};

#pragma unroll
        for (int ks = 0; ks < 4; ++ks) {
            bf16x8 af[6], bfv[6];
#pragma unroll
            for (int i = 0; i < 6; ++i)
                af[i] = *reinterpret_cast<const bf16x8*>(
                    &Ks[sbase + i * 16 + l16][ks * 32 + quad * 8]);
#pragma unroll
            for (int j = 0; j < 6; ++j)
                bfv[j] = *reinterpret_cast<const bf16x8*>(
                    &Qs[tbase + j * 16 + l16][ks * 32 + quad * 8]);
#pragma unroll
            for (int i = 0; i < 6; ++i)
#pragma unroll
                for (int j = 0; j < 6; ++j)
                    acc[i][j] = MFMA(af[i], bfv[j], acc[i][j]);
        }

        // Epilogue: v = acc * sig[s][t];  s = sbase+i*16+quad*4+r,
        //                                 t = tbase+j*16+l16
        float pt[6];
#pragma unroll
        for (int j = 0; j < 6; ++j) pt[j] = -3.0e38f;
#pragma unroll
        for (int i = 0; i < 6; ++i) {
            int srow = sbase + i * 16 + quad * 4;
            float ps0 = -3.0e38f, ps1 = -3.0e38f, ps2 = -3.0e38f, ps3 = -3.0e38f;
#pragma unroll
            for (int j = 0; j < 6; ++j) {
                int t = tbase + j * 16 + l16;
                // sig is symmetric: sig[s][t] == sig[t][s]; read 4 consecutive s
                bf16x4 sg = *reinterpret_cast<const bf16x4*>(sig_bf + t * 192 + srow);
                float v0 = acc[i][j][0] * (float)sg[0];
                float v1 = acc[i][j][1] * (float)sg[1];
                float v2 = acc[i][j][2] * (float)sg[2];
                float v3 = acc[i][j][3] * (float)sg[3];
                ps0 = fmaxf(ps0, v0); ps1 = fmaxf(ps1, v1);
                ps2 = fmaxf(ps2, v2); ps3 = fmaxf(ps3, v3);
                pt[j] = fmaxf(pt[j], fmaxf(fmaxf(v0, v1), fmaxf(v2, v3)));
            }
            red2[srow + 0][wt * 16 + l16] = ps0;
            red2[srow + 1][wt * 16 + l16] = ps1;
            red2[srow + 2][wt * 16 + l16] = ps2;
            red2[srow + 3][wt * 16 + l16] = ps3;
        }
#pragma unroll
        for (int j = 0; j < 6; ++j) {
            pt[j] = fmaxf(pt[j], __shfl_xor(pt[j], 16, 64));
            pt[j] = fmaxf(pt[j], __shfl_xor(pt[j], 32, 64));
        }
        if (quad == 0) {
#pragma unroll
            for (int j = 0; j < 6; ++j)
                redT[tbase + j * 16 + l16][ws] = pt[j];
        }
        __syncthreads();   // reductions ready

        if (tid < 192) {
            size_t obase = ((size_t)(q * 128 + kidx)) * 2 * 192;
            // row 2p: max over s, indexed by t
            float m0 = fmaxf(redT[tid][0], redT[tid][1]);
            Sred[obase + tid] = (__bf16)(m0 * g1c + b1v);
            // row 2p+1: max over t, indexed by s
            float m1 = -3.0e38f;
            const f32x4* rp = reinterpret_cast<const f32x4*>(&red2[tid][0]);
#pragma unroll
            for (int u = 0; u < 8; ++u) {
                f32x4 vv = rp[u];
                m1 = fmaxf(m1, fmaxf(fmaxf(vv[0], vv[1]), fmaxf(vv[2], vv[3])));
            }
            Sred[obase + 192 + tid] = (__bf16)(m1 * g1c + b1v);
        }
        // next iteration's Ks staging is safe: all Ks reads happened before the
        // barrier above; red2/redT rewrites are fenced by the post-stage barrier.
    }
}

// ---------------------------------------------------------------------------
// C: fused fc2 + bn2 + relu + fc3 + pair-sum + bn3.  32 Sred rows per block,
//    each wave covers 512 of the 2048 ff columns, fc3 dot accumulated inline.
// ---------------------------------------------------------------------------
__launch_bounds__(256, 4)
__global__ void mlp_kernel(const __bf16* __restrict__ Sred,
                           const __bf16* __restrict__ fc2w_bf,
                           const float* __restrict__ h2,
                           const float* __restrict__ bb2,
                           const float* __restrict__ f3,
                           const float* __restrict__ fc3b,
                           const float* __restrict__ bn3g,
                           const float* __restrict__ bn3b,
                           float* __restrict__ out)
{
    __shared__ __bf16 As[32][200];       // 32 rows x 192 (+8 pad)
    __shared__ float  psum_lds[4][32];
    int bx = blockIdx.x, tid = threadIdx.x;
    const __bf16* asrc = Sred + (size_t)bx * (32 * 192);
#pragma unroll
    for (int it = 0; it < 3; ++it) {     // 6144 bf16
        int e = (it * 256 + tid) * 8;
        int r = e / 192, c = e - r * 192;
        *reinterpret_cast<bf16x8*>(&As[r][c]) =
            *reinterpret_cast<const bf16x8*>(asrc + e);
    }
    __syncthreads();

    int wv = tid >> 6, lane = tid & 63, quad = lane >> 4, l16 = lane & 15;
    bf16x8 af[2][6];                     // hoisted A-fragments (reused 32x)
#pragma unroll
    for (int m = 0; m < 2; ++m)
#pragma unroll
        for (int kk = 0; kk < 6; ++kk)
            af[m][kk] = *reinterpret_cast<const bf16x8*>(
                &As[m * 16 + l16][kk * 32 + quad * 8]);

    float ps[2][4] = {{0.f, 0.f, 0.f, 0.f}, {0.f, 0.f, 0.f, 0.f}};
    for (int nt = 0; nt < 32; ++nt) {
        int n0 = wv * 512 + nt * 16;
        f32x4 acc0 = (f32x4){0.f, 0.f, 0.f, 0.f};
        f32x4 acc1 = (f32x4){0.f, 0.f, 0.f, 0.f};
        const __bf16* bp = fc2w_bf + (size_t)(n0 + l16) * 192 + quad * 8;
#pragma unroll
        for (int kk = 0; kk < 6; ++kk) {
            bf16x8 b = *reinterpret_cast<const bf16x8*>(bp + kk * 32);
            acc0 = MFMA(af[0][kk], b, acc0);
            acc1 = MFMA(af[1][kk], b, acc1);
        }
        int n = n0 + l16;
        float hh = h2[n], bb = bb2[n], ffv = f3[n];
#pragma unroll
        for (int r = 0; r < 4; ++r) {
            ps[0][r] += fmaxf(acc0[r] * hh + bb, 0.f) * ffv;
            ps[1][r] += fmaxf(acc1[r] * hh + bb, 0.f) * ffv;
        }
    }
#pragma unroll
    for (int m = 0; m < 2; ++m)
#pragma unroll
        for (int r = 0; r < 4; ++r) {
            float v = ps[m][r];
            v += __shfl_xor(v, 1, 64);
            v += __shfl_xor(v, 2, 64);
            v += __shfl_xor(v, 4, 64);
            v += __shfl_xor(v, 8, 64);
            if (l16 == 0) psum_lds[wv][m * 16 + quad * 4 + r] = v;
        }
    __syncthreads();
    if (tid < 16) {
        float s = 0.f;
#pragma unroll
        for (int w = 0; w < 4; ++w)
            s += psum_lds[w][2 * tid] + psum_lds[w][2 * tid + 1];
        const float c1 = rsqrtf(1.f + 1e-5f);
        out[bx * 16 + tid] = (s + 2.f * fc3b[0]) * (bn3g[0] * c1) + bn3b[0];
    }
}

// ---------------------------------------------------------------------------
extern "C" void kernel_launch(void* const* d_in, const int* in_sizes, int n_in,
                              void* d_out, int out_size, void* d_ws, size_t ws_size,
                              hipStream_t stream)
{
    const float* q_feat = (const float*)d_in[0];
    const float* g_feat = (const float*)d_in[1];
    const float* se     = (const float*)d_in[2];
    const float* fc0w   = (const float*)d_in[3];
    const float* fc0b   = (const float*)d_in[4];
    const float* fc2w   = (const float*)d_in[5];
    const float* fc2b   = (const float*)d_in[6];
    const float* fc3w   = (const float*)d_in[7];
    const float* fc3b   = (const float*)d_in[8];
    const float* bn1g   = (const float*)d_in[9];
    const float* bn1b   = (const float*)d_in[10];
    const float* bn2g   = (const float*)d_in[11];
    const float* bn2b   = (const float*)d_in[12];
    const float* bn3g   = (const float*)d_in[13];
    const float* bn3b   = (const float*)d_in[14];
    float* out = (float*)d_out;

    char* ws = (char*)d_ws;
    __bf16* qk_bf   = (__bf16*)(ws);                 //  9,437,184 B
    __bf16* sig_bf  = (__bf16*)(ws +  9437184);      //     73,728 B
    __bf16* fc0w_bf = (__bf16*)(ws +  9510912);      //     32,768 B
    __bf16* fc2w_bf = (__bf16*)(ws +  9543680);      //    786,432 B
    float*  h2      = (float*) (ws + 10330112);      //      8,192 B
    float*  bb2     = (float*) (ws + 10338304);      //      8,192 B
    float*  f3      = (float*) (ws + 10346496);      //      8,192 B
    __bf16* Sred    = (__bf16*)(ws + 10354688);      //  6,291,456 B  (~16.6 MB total)

    prep_kernel<<<256, 256, 0, stream>>>(se, fc0w, fc2w, fc2b, bn2g, bn2b, fc3w,
                                         sig_bf, fc0w_bf, fc2w_bf, h2, bb2, f3);
    qkproj_kernel<<<1152, 256, 0, stream>>>(q_feat, g_feat, fc0w_bf, fc0b, qk_bf);
    score_kernel<<<1024, 256, 0, stream>>>(qk_bf, sig_bf, bn1g, bn1b, Sred);
    mlp_kernel<<<512, 256, 0, stream>>>(Sred, fc2w_bf, h2, bb2, f3,
                                        fc3b, bn3g, bn3b, out);
}

// Round 2
// 273.544 us; speedup vs baseline: 1.1291x; 1.1291x over previous
//
#include <hip/hip_runtime.h>

// Shapes (fixed by the problem)
#define LQ 64
#define LK 128
#define LL 192
#define DD 128
#define FF 2048

typedef __attribute__((__ext_vector_type__(8))) __bf16 bf16x8;
typedef __attribute__((__ext_vector_type__(4))) __bf16 bf16x4;
typedef __attribute__((__ext_vector_type__(4))) float  f32x4;

#define MFMA(a, b, c) __builtin_amdgcn_mfma_f32_16x16x32_bf16((a), (b), (c), 0, 0, 0)

// ---------------------------------------------------------------------------
// A0: prep — sigmoid(score_embed) as bf16, bf16 copies of fc0_w / fc2_w,
//     combined per-ff constants for the fused fc2/bn2/relu/fc3 epilogue.
// ---------------------------------------------------------------------------
__global__ void prep_kernel(const float* __restrict__ se,
                            const float* __restrict__ fc0w,
                            const float* __restrict__ fc2w,
                            const float* __restrict__ fc2b,
                            const float* __restrict__ bn2g,
                            const float* __restrict__ bn2b,
                            const float* __restrict__ fc3w,
                            __bf16* __restrict__ sig_bf,
                            __bf16* __restrict__ fc0w_bf,
                            __bf16* __restrict__ fc2w_bf,
                            float* __restrict__ h2,
                            float* __restrict__ bb2,
                            float* __restrict__ f3)
{
    int i0 = blockIdx.x * blockDim.x + threadIdx.x;
    int stride = gridDim.x * blockDim.x;
    const float c1 = rsqrtf(1.f + 1e-5f);
    for (int i = i0; i < LL * LL; i += stride)
        sig_bf[i] = (__bf16)(1.f / (1.f + __expf(-se[i])));
    for (int i = i0; i < DD * DD; i += stride)
        fc0w_bf[i] = (__bf16)fc0w[i];
    for (int i = i0; i < FF * LL; i += stride)
        fc2w_bf[i] = (__bf16)fc2w[i];
    for (int i = i0; i < FF; i += stride) {
        float h = bn2g[i] * c1;           // bn2 scale (beta2 added below)
        h2[i]  = h;
        bb2[i] = fc2b[i] * h + bn2b[i];   // (dot + fc2b)*h + beta2 = dot*h + bb2
        f3[i]  = fc3w[i];
    }
}

// ---------------------------------------------------------------------------
// A1: query/key projection  y = X @ fc0_w^T + fc0_b, output bf16 [36864][128]
//     rows 0..12287 = query (from q_feat), 12288..36863 = key (from g_feat)
// ---------------------------------------------------------------------------
__launch_bounds__(256, 2)
__global__ void qkproj_kernel(const float* __restrict__ qf,
                              const float* __restrict__ gf,
                              const __bf16* __restrict__ w_bf,
                              const float* __restrict__ bias,
                              __bf16* __restrict__ qk_bf)
{
    __shared__ __bf16 Xs[32][136];    // 32 rows x 128 (+8 pad)
    __shared__ __bf16 Ws[128][136];   // fc0_w row-major [out_c][k]
    int bx = blockIdx.x, tid = threadIdx.x;
    const float* src = (bx < 384) ? (qf + (size_t)bx * (32 * 128))
                                  : (gf + (size_t)(bx - 384) * (32 * 128));
#pragma unroll
    for (int it = 0; it < 4; ++it) {             // 4096 floats
        int e = (it * 256 + tid) * 4;
        int r = e >> 7, c = e & 127;
        float4 v = *reinterpret_cast<const float4*>(src + e);
        bf16x4 xv;
        xv[0] = (__bf16)v.x; xv[1] = (__bf16)v.y;
        xv[2] = (__bf16)v.z; xv[3] = (__bf16)v.w;
        *reinterpret_cast<bf16x4*>(&Xs[r][c]) = xv;
    }
#pragma unroll
    for (int it = 0; it < 8; ++it) {             // 16384 bf16
        int e = (it * 256 + tid) * 8;
        int r = e >> 7, c = e & 127;
        *reinterpret_cast<bf16x8*>(&Ws[r][c]) =
            *reinterpret_cast<const bf16x8*>(w_bf + e);
    }
    __syncthreads();

    int wv = tid >> 6, lane = tid & 63, quad = lane >> 4, l16 = lane & 15;
    int n0 = wv * 32;                            // wave's 32 output cols
    f32x4 acc[2][2];
#pragma unroll
    for (int m = 0; m < 2; ++m)
#pragma unroll
        for (int n = 0; n < 2; ++n) acc[m][n] = (f32x4){0.f, 0.f, 0.f, 0.f};
#pragma unroll
    for (int ks = 0; ks < 4; ++ks) {
        bf16x8 a0 = *reinterpret_cast<const bf16x8*>(&Xs[l16][ks * 32 + quad * 8]);
        bf16x8 a1 = *reinterpret_cast<const bf16x8*>(&Xs[16 + l16][ks * 32 + quad * 8]);
        bf16x8 b0 = *reinterpret_cast<const bf16x8*>(&Ws[n0 + l16][ks * 32 + quad * 8]);
        bf16x8 b1 = *reinterpret_cast<const bf16x8*>(&Ws[n0 + 16 + l16][ks * 32 + quad * 8]);
        acc[0][0] = MFMA(a0, b0, acc[0][0]);
        acc[0][1] = MFMA(a0, b1, acc[0][1]);
        acc[1][0] = MFMA(a1, b0, acc[1][0]);
        acc[1][1] = MFMA(a1, b1, acc[1][1]);
    }
#pragma unroll
    for (int mt = 0; mt < 2; ++mt)
#pragma unroll
        for (int nt = 0; nt < 2; ++nt) {
            int colg = n0 + nt * 16 + l16;
            float bv = bias[colg];
#pragma unroll
            for (int r = 0; r < 4; ++r) {
                int rowg = bx * 32 + mt * 16 + quad * 4 + r;
                qk_bf[(size_t)rowg * 128 + colg] = (__bf16)(acc[mt][nt][r] + bv);
            }
        }
}

// ---------------------------------------------------------------------------
// B: per-pair score GEMM + sigmoid-modulation + dual max-reduce (dominant).
//    512 threads = 8 waves in a 2(s-half) x 4(t-quarter) grid; each wave owns
//    a 96x48 quadrant (acc[6][3]).  sig for the wave's quadrant lives in
//    registers (loaded once, reused for all 8 keys).  Next K tile is
//    register-prefetched before the MFMA block so global latency hides under
//    MFMA + epilogue.
// ---------------------------------------------------------------------------
__launch_bounds__(512, 2)
__global__ void score_kernel(const __bf16* __restrict__ qk_bf,
                             const __bf16* __restrict__ sig_bf,
                             const float* __restrict__ bn1g,
                             const float* __restrict__ bn1b,
                             __bf16* __restrict__ Sred)
{
    __shared__ __bf16 Qs[192][136];   // query rows [t][d], +8 pad
    __shared__ __bf16 Ks[192][136];   // key rows   [s][d], +8 pad
    __shared__ float  red2[192][20];  // per-s partial maxes, 16 cols (+4 pad)
    __shared__ float  redT[192][2];   // per-t partial maxes from the 2 s-halves

    int tid = threadIdx.x;
    int q = blockIdx.x >> 4;
    int kbase = (blockIdx.x & 15) << 3;
    int wv = tid >> 6, lane = tid & 63, quad = lane >> 4, l16 = lane & 15;
    int ws = wv >> 2, wt = wv & 3;          // 2 x 4 wave grid
    int sbase = ws * 96, tbase = wt * 48;

    // stage Qs and the first K tile
    const __bf16* qsrc  = qk_bf + (size_t)q * (192 * 128);
    const __bf16* ksrc0 = qk_bf + (size_t)(12288 + kbase * 192) * 128;
#pragma unroll
    for (int it = 0; it < 6; ++it) {         // 24576 bf16 each
        int e = (it * 512 + tid) * 8;
        int r = e >> 7, c = e & 127;
        *reinterpret_cast<bf16x8*>(&Qs[r][c]) =
            *reinterpret_cast<const bf16x8*>(qsrc + e);
        *reinterpret_cast<bf16x8*>(&Ks[r][c]) =
            *reinterpret_cast<const bf16x8*>(ksrc0 + e);
    }

    // this wave's sig quadrant -> registers (sig is symmetric: read [t][s..s+3])
    bf16x4 sg[6][3];
#pragma unroll
    for (int i = 0; i < 6; ++i) {
        int srow = sbase + i * 16 + quad * 4;
#pragma unroll
        for (int j = 0; j < 3; ++j) {
            int t = tbase + j * 16 + l16;
            sg[i][j] = *reinterpret_cast<const bf16x4*>(sig_bf + t * 192 + srow);
        }
    }
    const float g1c = bn1g[0] * rsqrtf(1.f + 1e-5f);
    const float b1v = bn1b[0];
    __syncthreads();

    for (int kk = 0; kk < 8; ++kk) {
        // register-prefetch the next K tile (latency hidden under MFMA)
        bf16x8 pre[6];
        if (kk < 7) {
            const __bf16* ksrc =
                qk_bf + (size_t)(12288 + (kbase + kk + 1) * 192) * 128;
#pragma unroll
            for (int it = 0; it < 6; ++it)
                pre[it] = *reinterpret_cast<const bf16x8*>(ksrc + (it * 512 + tid) * 8);
        }

        f32x4 acc[6][3];
#pragma unroll
        for (int i = 0; i < 6; ++i)
#pragma unroll
            for (int j = 0; j < 3; ++j) acc[i][j] = (f32x4){0.f, 0.f, 0.f, 0.f};

#pragma unroll
        for (int ks = 0; ks < 4; ++ks) {
            bf16x8 af[6], bfv[3];
#pragma unroll
            for (int i = 0; i < 6; ++i)
                af[i] = *reinterpret_cast<const bf16x8*>(
                    &Ks[sbase + i * 16 + l16][ks * 32 + quad * 8]);
#pragma unroll
            for (int j = 0; j < 3; ++j)
                bfv[j] = *reinterpret_cast<const bf16x8*>(
                    &Qs[tbase + j * 16 + l16][ks * 32 + quad * 8]);
#pragma unroll
            for (int i = 0; i < 6; ++i)
#pragma unroll
                for (int j = 0; j < 3; ++j)
                    acc[i][j] = MFMA(af[i], bfv[j], acc[i][j]);
        }

        // Epilogue: v = acc * sig[s][t];  s = sbase+i*16+quad*4+r,
        //                                 t = tbase+j*16+l16
        float pt[3] = {-3.0e38f, -3.0e38f, -3.0e38f};
#pragma unroll
        for (int i = 0; i < 6; ++i) {
            int srow = sbase + i * 16 + quad * 4;
            float ps0 = -3.0e38f, ps1 = -3.0e38f, ps2 = -3.0e38f, ps3 = -3.0e38f;
#pragma unroll
            for (int j = 0; j < 3; ++j) {
                float v0 = acc[i][j][0] * (float)sg[i][j][0];
                float v1 = acc[i][j][1] * (float)sg[i][j][1];
                float v2 = acc[i][j][2] * (float)sg[i][j][2];
                float v3 = acc[i][j][3] * (float)sg[i][j][3];
                ps0 = fmaxf(ps0, v0); ps1 = fmaxf(ps1, v1);
                ps2 = fmaxf(ps2, v2); ps3 = fmaxf(ps3, v3);
                pt[j] = fmaxf(pt[j], fmaxf(fmaxf(v0, v1), fmaxf(v2, v3)));
            }
            // reduce over l16 bits 2,3 -> 4 partials per 16 t-lanes
            ps0 = fmaxf(ps0, __shfl_xor(ps0, 4, 64));
            ps0 = fmaxf(ps0, __shfl_xor(ps0, 8, 64));
            ps1 = fmaxf(ps1, __shfl_xor(ps1, 4, 64));
            ps1 = fmaxf(ps1, __shfl_xor(ps1, 8, 64));
            ps2 = fmaxf(ps2, __shfl_xor(ps2, 4, 64));
            ps2 = fmaxf(ps2, __shfl_xor(ps2, 8, 64));
            ps3 = fmaxf(ps3, __shfl_xor(ps3, 4, 64));
            ps3 = fmaxf(ps3, __shfl_xor(ps3, 8, 64));
            if ((lane & 12) == 0) {          // l16 in 0..3
                red2[srow + 0][wt * 4 + l16] = ps0;
                red2[srow + 1][wt * 4 + l16] = ps1;
                red2[srow + 2][wt * 4 + l16] = ps2;
                red2[srow + 3][wt * 4 + l16] = ps3;
            }
        }
#pragma unroll
        for (int j = 0; j < 3; ++j) {
            pt[j] = fmaxf(pt[j], __shfl_xor(pt[j], 16, 64));
            pt[j] = fmaxf(pt[j], __shfl_xor(pt[j], 32, 64));
        }
        if (quad == 0) {
#pragma unroll
            for (int j = 0; j < 3; ++j)
                redT[tbase + j * 16 + l16][ws] = pt[j];
        }
        __syncthreads();   // MFMA reads of Ks done; red2/redT complete

        if (kk < 7) {
#pragma unroll
            for (int it = 0; it < 6; ++it) {
                int e = (it * 512 + tid) * 8;
                int r = e >> 7, c = e & 127;
                *reinterpret_cast<bf16x8*>(&Ks[r][c]) = pre[it];
            }
        }
        if (tid < 192) {
            size_t obase = ((size_t)(q * 128 + kbase + kk)) * 2 * 192;
            // row 2p: max over s, indexed by t
            float m0 = fmaxf(redT[tid][0], redT[tid][1]);
            Sred[obase + tid] = (__bf16)(m0 * g1c + b1v);
            // row 2p+1: max over t, indexed by s
            f32x4 a0 = *reinterpret_cast<const f32x4*>(&red2[tid][0]);
            f32x4 a1 = *reinterpret_cast<const f32x4*>(&red2[tid][4]);
            f32x4 a2 = *reinterpret_cast<const f32x4*>(&red2[tid][8]);
            f32x4 a3 = *reinterpret_cast<const f32x4*>(&red2[tid][12]);
            f32x4 mm;
            mm[0] = fmaxf(fmaxf(a0[0], a1[0]), fmaxf(a2[0], a3[0]));
            mm[1] = fmaxf(fmaxf(a0[1], a1[1]), fmaxf(a2[1], a3[1]));
            mm[2] = fmaxf(fmaxf(a0[2], a1[2]), fmaxf(a2[2], a3[2]));
            mm[3] = fmaxf(fmaxf(a0[3], a1[3]), fmaxf(a2[3], a3[3]));
            float m1 = fmaxf(fmaxf(mm[0], mm[1]), fmaxf(mm[2], mm[3]));
            Sred[obase + 192 + tid] = (__bf16)(m1 * g1c + b1v);
        }
        __syncthreads();   // Ks writes visible; red2 free for next iteration
    }
}

// ---------------------------------------------------------------------------
// C: fused fc2 + bn2 + relu + fc3 + pair-sum + bn3.  64 Sred rows per block
//    (24 MFMA per 6KB fc2w read -> no longer L2-BW-bound), each wave covers
//    512 of the 2048 ff columns, fc3 dot accumulated inline.
// ---------------------------------------------------------------------------
__launch_bounds__(256, 2)
__global__ void mlp_kernel(const __bf16* __restrict__ Sred,
                           const __bf16* __restrict__ fc2w_bf,
                           const float* __restrict__ h2,
                           const float* __restrict__ bb2,
                           const float* __restrict__ f3,
                           const float* __restrict__ fc3b,
                           const float* __restrict__ bn3g,
                           const float* __restrict__ bn3b,
                           float* __restrict__ out)
{
    __shared__ __bf16 As[64][200];       // 64 rows x 192 (+8 pad)
    __shared__ float  psum_lds[4][64];
    int bx = blockIdx.x, tid = threadIdx.x;
    const __bf16* asrc = Sred + (size_t)bx * (64 * 192);
#pragma unroll
    for (int it = 0; it < 6; ++it) {     // 12288 bf16
        int e = (it * 256 + tid) * 8;
        int r = e / 192, c = e - r * 192;
        *reinterpret_cast<bf16x8*>(&As[r][c]) =
            *reinterpret_cast<const bf16x8*>(asrc + e);
    }
    __syncthreads();

    int wv = tid >> 6, lane = tid & 63, quad = lane >> 4, l16 = lane & 15;
    bf16x8 af[4][6];                     // hoisted A-fragments (reused 32x)
#pragma unroll
    for (int m = 0; m < 4; ++m)
#pragma unroll
        for (int kk = 0; kk < 6; ++kk)
            af[m][kk] = *reinterpret_cast<const bf16x8*>(
                &As[m * 16 + l16][kk * 32 + quad * 8]);

    float ps[4][4] = {{0.f,0.f,0.f,0.f},{0.f,0.f,0.f,0.f},
                      {0.f,0.f,0.f,0.f},{0.f,0.f,0.f,0.f}};
    for (int nt = 0; nt < 32; ++nt) {
        int n0 = wv * 512 + nt * 16;
        f32x4 acc[4];
#pragma unroll
        for (int m = 0; m < 4; ++m) acc[m] = (f32x4){0.f, 0.f, 0.f, 0.f};
        const __bf16* bp = fc2w_bf + (size_t)(n0 + l16) * 192 + quad * 8;
#pragma unroll
        for (int kk = 0; kk < 6; ++kk) {
            bf16x8 b = *reinterpret_cast<const bf16x8*>(bp + kk * 32);
#pragma unroll
            for (int m = 0; m < 4; ++m) acc[m] = MFMA(af[m][kk], b, acc[m]);
        }
        int n = n0 + l16;
        float hh = h2[n], bb = bb2[n], ffv = f3[n];
#pragma unroll
        for (int m = 0; m < 4; ++m)
#pragma unroll
            for (int r = 0; r < 4; ++r)
                ps[m][r] += fmaxf(acc[m][r] * hh + bb, 0.f) * ffv;
    }
#pragma unroll
    for (int m = 0; m < 4; ++m)
#pragma unroll
        for (int r = 0; r < 4; ++r) {
            float v = ps[m][r];
            v += __shfl_xor(v, 1, 64);
            v += __shfl_xor(v, 2, 64);
            v += __shfl_xor(v, 4, 64);
            v += __shfl_xor(v, 8, 64);
            if (l16 == 0) psum_lds[wv][m * 16 + quad * 4 + r] = v;
        }
    __syncthreads();
    if (tid < 32) {
        float s = 0.f;
#pragma unroll
        for (int w = 0; w < 4; ++w)
            s += psum_lds[w][2 * tid] + psum_lds[w][2 * tid + 1];
        const float c1 = rsqrtf(1.f + 1e-5f);
        out[bx * 32 + tid] = (s + 2.f * fc3b[0]) * (bn3g[0] * c1) + bn3b[0];
    }
}

// ---------------------------------------------------------------------------
extern "C" void kernel_launch(void* const* d_in, const int* in_sizes, int n_in,
                              void* d_out, int out_size, void* d_ws, size_t ws_size,
                              hipStream_t stream)
{
    const float* q_feat = (const float*)d_in[0];
    const float* g_feat = (const float*)d_in[1];
    const float* se     = (const float*)d_in[2];
    const float* fc0w   = (const float*)d_in[3];
    const float* fc0b   = (const float*)d_in[4];
    const float* fc2w   = (const float*)d_in[5];
    const float* fc2b   = (const float*)d_in[6];
    const float* fc3w   = (const float*)d_in[7];
    const float* fc3b   = (const float*)d_in[8];
    const float* bn1g   = (const float*)d_in[9];
    const float* bn1b   = (const float*)d_in[10];
    const float* bn2g   = (const float*)d_in[11];
    const float* bn2b   = (const float*)d_in[12];
    const float* bn3g   = (const float*)d_in[13];
    const float* bn3b   = (const float*)d_in[14];
    float* out = (float*)d_out;

    char* ws = (char*)d_ws;
    __bf16* qk_bf   = (__bf16*)(ws);                 //  9,437,184 B
    __bf16* sig_bf  = (__bf16*)(ws +  9437184);      //     73,728 B
    __bf16* fc0w_bf = (__bf16*)(ws +  9510912);      //     32,768 B
    __bf16* fc2w_bf = (__bf16*)(ws +  9543680);      //    786,432 B
    float*  h2      = (float*) (ws + 10330112);      //      8,192 B
    float*  bb2     = (float*) (ws + 10338304);      //      8,192 B
    float*  f3      = (float*) (ws + 10346496);      //      8,192 B
    __bf16* Sred    = (__bf16*)(ws + 10354688);      //  6,291,456 B  (~16.6 MB total)

    prep_kernel<<<256, 256, 0, stream>>>(se, fc0w, fc2w, fc2b, bn2g, bn2b, fc3w,
                                         sig_bf, fc0w_bf, fc2w_bf, h2, bb2, f3);
    qkproj_kernel<<<1152, 256, 0, stream>>>(q_feat, g_feat, fc0w_bf, fc0b, qk_bf);
    score_kernel<<<1024, 512, 0, stream>>>(qk_bf, sig_bf, bn1g, bn1b, Sred);
    mlp_kernel<<<256, 256, 0, stream>>>(Sred, fc2w_bf, h2, bb2, f3,
                                        fc3b, bn3g, bn3b, out);
}